// Round 14
// baseline (3551.161 us; speedup 1.0000x reference)
//
#include <hip/hip_runtime.h>

typedef _Float16 f16;
typedef _Float16 f16x8 __attribute__((ext_vector_type(8)));
typedef float f32x4 __attribute__((ext_vector_type(4)));

#define B_ 512
#define T_ 128
#define I_ 64
#define H_ 512
#define O_ 64
#define L_ 300
#define OUTSTR (L_*O_)
#define NBLK 256

// ---------------------------------------------------------------------------
// Prologue kernels (verified R0/R1/R3). Packed B layout (MFMA 16x16x32 f16):
//   flat = ((ntile_global*KSTEPS + kstep)*64 + lane)*8 + elem
//   value = W[k][col], k = kstep*32 + (lane>>4)*8 + elem, col = lane&15
// ---------------------------------------------------------------------------

__global__ void k_zero_h(f16* h) {
  int i = blockIdx.x*256 + threadIdx.x;
  if (i < B_*H_) h[i] = (f16)0.f;
}

__global__ void k_cvt_x(const float* __restrict__ x, f16* __restrict__ x16) {
  int p = blockIdx.x*256 + threadIdx.x;
  if (p >= T_*B_*I_) return;
  int i = p & 63, b = (p >> 6) & 511, t = p >> 15;
  x16[p] = (f16)x[((size_t)b*T_ + t)*I_ + i];
}

__global__ void k_fuse(const float* __restrict__ Wo, const float* __restrict__ Wih,
                       float* __restrict__ Wf) {
  int p = blockIdx.x*256 + threadIdx.x;
  if (p >= 1536*512) return;
  int k = p & 511, j3 = p >> 9;
  float s = 0.f;
  for (int o = 0; o < 64; ++o) s += Wo[(size_t)o*H_ + k] * Wih[(size_t)j3*I_ + o];
  Wf[p] = s;
}

__global__ void k_bf(const float* __restrict__ bo, const float* __restrict__ Wih,
                     float* __restrict__ bf) {
  int j3 = blockIdx.x*256 + threadIdx.x;
  if (j3 >= 1536) return;
  float s = 0.f;
  for (int o = 0; o < 64; ++o) s += bo[o]*Wih[(size_t)j3*I_ + o];
  bf[j3] = s;
}

__global__ void k_pack_enc(const float* __restrict__ Whh, const float* __restrict__ Wih,
                           f16* __restrict__ We) {
  int p = blockIdx.x*256 + threadIdx.x;
  if (p >= 128*18*512) return;
  int i = p & 7, l = (p >> 3) & 63, ks = (p >> 9) % 18, ntg = p / (18*512);
  int g = ntg >> 2, nti = ntg & 3, c = l & 15;
  int j = g*16 + c, k = ks*32 + ((l>>4)<<3) + i;
  float v = 0.f;
  if (nti == 0)      v = (k < 512) ? Whh[(size_t)j*H_ + k]        : Wih[(size_t)j*I_ + (k-512)];
  else if (nti == 1) v = (k < 512) ? Whh[(size_t)(512+j)*H_ + k]  : Wih[(size_t)(512+j)*I_ + (k-512)];
  else if (nti == 2) v = (k < 512) ? Whh[(size_t)(1024+j)*H_ + k] : 0.f;
  else               v = (k >= 512)? Wih[(size_t)(1024+j)*I_ + (k-512)] : 0.f;
  We[p] = (f16)v;
}

__global__ void k_pack_dec(const float* __restrict__ Whh, const float* __restrict__ Wo,
                           const float* __restrict__ Wf, f16* __restrict__ Wd) {
  int p = blockIdx.x*256 + threadIdx.x;
  if (p >= 160*16*512) return;
  int i = p & 7, l = (p >> 3) & 63, ks = (p >> 9) & 15, ntg = p >> 13;
  int g = ntg/5, nti = ntg%5, c = l & 15;
  int j = g*16 + c, k = ks*32 + ((l>>4)<<3) + i;
  float v;
  if (nti == 0)      v = Whh[(size_t)j*H_+k]       + Wf[(size_t)j*512 + k];
  else if (nti == 1) v = Whh[(size_t)(512+j)*H_+k] + Wf[(size_t)(512+j)*512 + k];
  else if (nti == 2) v = Whh[(size_t)(1024+j)*H_+k];
  else if (nti == 3) v = Wf[(size_t)(1024+j)*512 + k];
  else               v = (c < 2) ? Wo[(size_t)(2*g+c)*H_ + k] : 0.f;
  Wd[p] = (f16)v;
}

__global__ void k_bias_enc(const float* __restrict__ bih, const float* __restrict__ bhh,
                           float* __restrict__ be) {
  int p = blockIdx.x*256 + threadIdx.x;
  if (p >= 2048) return;
  int c = p & 15, ntg = p >> 4, g = ntg >> 2, nti = ntg & 3, j = g*16 + c;
  float v;
  if (nti == 0)      v = bih[j] + bhh[j];
  else if (nti == 1) v = bih[512+j] + bhh[512+j];
  else if (nti == 2) v = bhh[1024+j];
  else               v = bih[1024+j];
  be[p] = v;
}

__global__ void k_bias_dec(const float* __restrict__ bih, const float* __restrict__ bhh,
                           const float* __restrict__ bo, const float* __restrict__ bf,
                           float* __restrict__ bd) {
  int p = blockIdx.x*256 + threadIdx.x;
  if (p >= 2560) return;
  int c = p & 15, ntg = p >> 4, g = ntg/5, nti = ntg%5, j = g*16 + c;
  float v;
  if (nti == 0)      v = bih[j] + bhh[j] + bf[j];
  else if (nti == 1) v = bih[512+j] + bhh[512+j] + bf[512+j];
  else if (nti == 2) v = bhh[1024+j];
  else if (nti == 3) v = bih[1024+j] + bf[1024+j];
  else               v = (c < 2) ? bo[2*g+c] : 0.f;
  bd[p] = v;
}

// ---------------------------------------------------------------------------
// R13 = R10 with the fast-path barrier moved to the XCD L2 while KEEPING the
// parallel per-block flag lines:
//   arrive = sc0 write-through store to own 64B flag line (R8-proven pub;
//            no RMW -> 32 arrivals in parallel, unlike R12's serial counter)
//   poll   = global_atomic_add +0 sc0 per lane on 32 DISTINCT lines (atomics
//            execute at the cache -> immune to the R2/R7/R9 stale-L1 hang;
//            distinct lines -> parallel at L2)
// Data path sc0 (R8), fallback LLC barrier (R6) verbatim.
// ---------------------------------------------------------------------------

__device__ __forceinline__ float sigmoidf_(float x){ return 1.f/(1.f + __expf(-x)); }
__device__ __forceinline__ float tanhf_(float x){ return 1.f - 2.f/(__expf(2.f*x) + 1.f); }

template<bool FA>
__device__ __forceinline__ f16x8 ldA(const f16* p) {     // coherent 16B load
  f16x8 r;
  if (FA) asm volatile("global_load_dwordx4 %0, %1, off sc0"     : "=&v"(r) : "v"(p));
  else    asm volatile("global_load_dwordx4 %0, %1, off sc0 sc1" : "=&v"(r) : "v"(p));
  return r;
}
__device__ __forceinline__ f16x8 ldP(const f16* p) {     // read-only (x16), cached
  f16x8 r;
  asm volatile("global_load_dwordx4 %0, %1, off" : "=&v"(r) : "v"(p));
  return r;
}
template<bool FA>
__device__ __forceinline__ void stH(f16* p, f16 h) {     // write-through 2B store
  unsigned b = (unsigned)__builtin_bit_cast(unsigned short, h);
  if (FA) asm volatile("global_store_short %0, %1, off sc0"     :: "v"(p), "v"(b) : "memory");
  else    asm volatile("global_store_short %0, %1, off sc0 sc1" :: "v"(p), "v"(b) : "memory");
}
__device__ __forceinline__ void vwait0() {
  asm volatile("s_waitcnt vmcnt(0)" ::: "memory");
  __builtin_amdgcn_sched_barrier(0);
}

// FALLBACK per-slab barrier: two-round LLC, compiler atomics (R6/R8-proven).
__device__ __forceinline__ void sbar_llc(unsigned* __restrict__ flags,
                                         unsigned* __restrict__ go,
                                         int bm, int g, unsigned tgt) {
  asm volatile("s_waitcnt vmcnt(0)" ::: "memory");
  __syncthreads();
  const int tid = threadIdx.x;
  if (g == 0) {
    if (tid < 64) {
      if (tid == 0)
        __hip_atomic_store(&flags[(bm*32)*16], tgt, __ATOMIC_RELAXED,
                           __HIP_MEMORY_SCOPE_AGENT);
      unsigned v;
      do {
        v = __hip_atomic_load(&flags[(bm*32 + (tid & 31))*16], __ATOMIC_RELAXED,
                              __HIP_MEMORY_SCOPE_AGENT);
      } while (!__all(v >= tgt));
      if (tid == 0)
        __hip_atomic_store(&go[bm*16], tgt, __ATOMIC_RELAXED,
                           __HIP_MEMORY_SCOPE_AGENT);
    }
  } else {
    if (tid == 0) {
      __hip_atomic_store(&flags[(bm*32 + g)*16], tgt, __ATOMIC_RELAXED,
                         __HIP_MEMORY_SCOPE_AGENT);
      while (__hip_atomic_load(&go[bm*16], __ATOMIC_RELAXED,
                               __HIP_MEMORY_SCOPE_AGENT) < tgt)
        __builtin_amdgcn_s_sleep(2);
    }
  }
  __syncthreads();
  __builtin_amdgcn_sched_barrier(0);
}

// FAST per-slab barrier: one round, XCD-local. Arrive: tid0 sc0 store to own
// flag line. Wait: wave 0, lane L polls flag L via atomic_add+0 sc0 (executes
// at the XCD L2; returns current value; L1 staleness impossible).
__device__ __forceinline__ void sbar_x(unsigned* __restrict__ flags,
                                       int bm, int g, unsigned tgt) {
  asm volatile("s_waitcnt vmcnt(0)" ::: "memory");  // h stores acked by L2
  __syncthreads();                                  // all 4 waves drained
  if (threadIdx.x < 64) {
    if (threadIdx.x == 0) {
      unsigned* fp = flags + (bm*32 + g)*16;
      asm volatile("global_store_dword %0, %1, off sc0"
                   :: "v"(fp), "v"(tgt) : "memory");
    }
    unsigned* pp = flags + (bm*32 + (threadIdx.x & 31))*16;
    for (;;) {
      unsigned v;
      asm volatile("global_atomic_add %0, %1, %2, off sc0\n\ts_waitcnt vmcnt(0)"
                   : "=&v"(v) : "v"(pp), "v"(0u) : "memory");
      if (__ballot(v >= tgt) == ~0ull) break;
    }
  }
  __syncthreads();
  __builtin_amdgcn_sched_barrier(0);
}

#define MFMA16(a,b,acc) __builtin_amdgcn_mfma_f32_16x16x32_f16(a, b, acc, 0, 0, 0)

template<bool FA>
__device__ __forceinline__ void run_loop(
    const f16* __restrict__ x16, const f16* __restrict__ We,
    const f16* __restrict__ Wd, const float* __restrict__ be,
    const float* __restrict__ bd, f16* __restrict__ h0, f16* __restrict__ h1,
    float* __restrict__ out, unsigned* __restrict__ flags,
    unsigned* __restrict__ go, f16* lds, int bm, int g) {
  const int tid = threadIdx.x, w = tid >> 6, lane = tid & 63;
  const int c = lane & 15, rq = lane >> 4;
  const int row0 = bm*64 + w*16 + c;       // A-fragment row
  const int rowb = bm*64 + w*16 + rq*4;    // C/D row base
  const int j = g*16 + c;

  // ---- encoder: stage K=512 h-part weights to LDS once; x-part in regs ----
  for (int it = 0; it < 16; ++it) {
    int idx = it*256 + tid;
    int nt = idx >> 10, r = idx & 1023;
    *(f16x8*)((char*)lds + (size_t)idx*16) =
        *(const f16x8*)((const char*)We + (size_t)(g*4+nt)*18432 + (size_t)r*16);
  }
  f16x8 bx0,bx1,bx2,bx3,bx4,bx5,bx6,bx7;
  {
    const char* base = (const char*)We + (size_t)lane*16 + 16*1024;
    bx0 = *(const f16x8*)(base + (size_t)(g*4+0)*18432);
    bx1 = *(const f16x8*)(base + (size_t)(g*4+1)*18432);
    bx2 = *(const f16x8*)(base + (size_t)(g*4+2)*18432);
    bx3 = *(const f16x8*)(base + (size_t)(g*4+3)*18432);
    bx4 = *(const f16x8*)(base + (size_t)(g*4+0)*18432 + 1024);
    bx5 = *(const f16x8*)(base + (size_t)(g*4+1)*18432 + 1024);
    bx6 = *(const f16x8*)(base + (size_t)(g*4+2)*18432 + 1024);
    bx7 = *(const f16x8*)(base + (size_t)(g*4+3)*18432 + 1024);
  }
  float br = be[(g*4+0)*16+c], bz = be[(g*4+1)*16+c];
  float bh = be[(g*4+2)*16+c], bi = be[(g*4+3)*16+c];
  float hprev[4] = {0.f, 0.f, 0.f, 0.f};   // h_in[rowb+i][j], owned by THIS
                                           // thread (h0 starts zeroed)
  __syncthreads();

  unsigned s = 0;   // global step index 0..426
  for (int t = 0; t < T_; ++t, ++s) {
    const f16* hin  = (t & 1) ? h1 : h0;
    f16*       hout = (t & 1) ? h0 : h1;
    const f16* xt = x16 + (size_t)t*B_*I_;
    f16x8 ha[16];
    #pragma unroll
    for (int ks = 0; ks < 16; ++ks)
      ha[ks] = ldA<FA>(hin + (size_t)row0*H_ + ks*32 + (rq<<3));
    f16x8 ax = ldP(xt + (size_t)row0*I_ + (rq<<3));
    f16x8 ay = ldP(xt + (size_t)row0*I_ + 32 + (rq<<3));
    vwait0();
    f32x4 a0={},a1={},a2={},a3={};
    #pragma unroll
    for (int ks = 0; ks < 16; ++ks) {
      a0 = MFMA16(ha[ks], *(const f16x8*)(lds + (0*16+ks)*512 + lane*8), a0);
      a1 = MFMA16(ha[ks], *(const f16x8*)(lds + (1*16+ks)*512 + lane*8), a1);
      a2 = MFMA16(ha[ks], *(const f16x8*)(lds + (2*16+ks)*512 + lane*8), a2);
      a3 = MFMA16(ha[ks], *(const f16x8*)(lds + (3*16+ks)*512 + lane*8), a3);
    }
    a0 = MFMA16(ax, bx0, a0); a1 = MFMA16(ax, bx1, a1);
    a2 = MFMA16(ax, bx2, a2); a3 = MFMA16(ax, bx3, a3);
    a0 = MFMA16(ay, bx4, a0); a1 = MFMA16(ay, bx5, a1);
    a2 = MFMA16(ay, bx6, a2); a3 = MFMA16(ay, bx7, a3);
    #pragma unroll
    for (int i = 0; i < 4; ++i) {
      float r = sigmoidf_(a0[i] + br);
      float z = sigmoidf_(a1[i] + bz);
      float n = tanhf_((a3[i] + bi) + r*(a2[i] + bh));
      f16 hv = (f16)((1.f - z)*n + z*hprev[i]);
      stH<FA>(hout + (size_t)(rowb+i)*H_ + j, hv);
      hprev[i] = (float)hv;
    }
    if (FA) sbar_x  (flags, bm, g, s+1);
    else    sbar_llc(flags, go, bm, g, s+1);
  }

  // ---- decoder: restage gate ntiles; y-ntile in regs ----
  __syncthreads();
  for (int it = 0; it < 16; ++it) {
    int idx = it*256 + tid;
    int nt = idx >> 10, r = idx & 1023;
    *(f16x8*)((char*)lds + (size_t)idx*16) =
        *(const f16x8*)((const char*)Wd + (size_t)(g*5+nt)*16384 + (size_t)r*16);
  }
  f16x8 yb[16];
  #pragma unroll
  for (int ks = 0; ks < 16; ++ks)
    yb[ks] = *(const f16x8*)((const char*)Wd + (size_t)(g*5+4)*16384
                             + (size_t)ks*1024 + (size_t)lane*16);
  float dr = bd[(g*5+0)*16+c], dz = bd[(g*5+1)*16+c];
  float dh = bd[(g*5+2)*16+c], di = bd[(g*5+3)*16+c], dy = bd[(g*5+4)*16+c];
  __syncthreads();

  for (int d = 0; d < L_-1; ++d, ++s) {
    const f16* hin  = (d & 1) ? h1 : h0;
    f16*       hout = (d & 1) ? h0 : h1;
    f16x8 ha[16];
    #pragma unroll
    for (int ks = 0; ks < 16; ++ks)
      ha[ks] = ldA<FA>(hin + (size_t)row0*H_ + ks*32 + (rq<<3));
    vwait0();
    f32x4 a0={},a1={},a2={},a3={},a4={};
    #pragma unroll
    for (int ks = 0; ks < 16; ++ks) {
      a0 = MFMA16(ha[ks], *(const f16x8*)(lds + (0*16+ks)*512 + lane*8), a0);
      a1 = MFMA16(ha[ks], *(const f16x8*)(lds + (1*16+ks)*512 + lane*8), a1);
      a2 = MFMA16(ha[ks], *(const f16x8*)(lds + (2*16+ks)*512 + lane*8), a2);
      a3 = MFMA16(ha[ks], *(const f16x8*)(lds + (3*16+ks)*512 + lane*8), a3);
      a4 = MFMA16(ha[ks], yb[ks], a4);
    }
    float* yo = out + (size_t)d*O_;
    #pragma unroll
    for (int i = 0; i < 4; ++i) {
      float r = sigmoidf_(a0[i] + dr);
      float z = sigmoidf_(a1[i] + dz);
      float n = tanhf_((a3[i] + di) + r*(a2[i] + dh));
      f16 hv = (f16)((1.f - z)*n + z*hprev[i]);
      stH<FA>(hout + (size_t)(rowb+i)*H_ + j, hv);
      hprev[i] = (float)hv;
      if (c < 2) yo[(size_t)(rowb+i)*OUTSTR + 2*g + c] = a4[i] + dy;
    }
    if (FA) sbar_x  (flags, bm, g, s+1);
    else    sbar_llc(flags, go, bm, g, s+1);
  }

  // ---- final y projection from h1 (written at d=298; slab-local) ----
  {
    f16x8 ha[16];
    #pragma unroll
    for (int ks = 0; ks < 16; ++ks)
      ha[ks] = ldA<FA>(h1 + (size_t)row0*H_ + ks*32 + (rq<<3));
    vwait0();
    f32x4 a4 = {};
    #pragma unroll
    for (int ks = 0; ks < 16; ++ks) a4 = MFMA16(ha[ks], yb[ks], a4);
    if (c < 2) {
      #pragma unroll
      for (int i = 0; i < 4; ++i)
        out[(size_t)(rowb+i)*OUTSTR + (size_t)(L_-1)*O_ + 2*g + c] = a4[i] + dy;
    }
  }
}

__global__ __launch_bounds__(256, 1) void k_persist(
    const f16* __restrict__ x16, const f16* __restrict__ We,
    const f16* __restrict__ Wd, const float* __restrict__ be,
    const float* __restrict__ bd, f16* __restrict__ h0, f16* __restrict__ h1,
    float* __restrict__ out, unsigned* __restrict__ stepFlags,
    unsigned* __restrict__ stepGo, unsigned* __restrict__ xcds,
    unsigned* __restrict__ verdict) {
  __shared__ f16 lds[32768];
  const int tid = threadIdx.x, bid = blockIdx.x;

  // ---- every block unconditionally publishes XCC_ID|8 (nonzero marker) ----
  if (tid == 0) {
    unsigned xcc;
    asm volatile("s_getreg_b32 %0, hwreg(HW_REG_XCC_ID)" : "=s"(xcc));
    __hip_atomic_store(&xcds[bid], (xcc & 7u) | 8u, __ATOMIC_RELAXED,
                       __HIP_MEMORY_SCOPE_AGENT);
  }
  // ---- block 0: wait all published, decide, publish verdict (acyclic) ----
  if (bid == 0 && tid < 64) {
    for (;;) {
      int ready = 1;
      for (int k2 = 0; k2 < 4; ++k2)
        ready &= (__hip_atomic_load(&xcds[tid*4 + k2], __ATOMIC_RELAXED,
                                    __HIP_MEMORY_SCOPE_AGENT) >= 8u);
      if (__ballot(ready != 0) == ~0ull) break;
      __builtin_amdgcn_s_sleep(2);
    }
    int okA = 1, okB = 1;
    for (int k2 = 0; k2 < 4; ++k2) {
      int b2 = tid*4 + k2;
      unsigned xv = __hip_atomic_load(&xcds[b2],         __ATOMIC_RELAXED, __HIP_MEMORY_SCOPE_AGENT);
      unsigned ra = __hip_atomic_load(&xcds[b2 & 7],     __ATOMIC_RELAXED, __HIP_MEMORY_SCOPE_AGENT);
      unsigned rb = __hip_atomic_load(&xcds[(b2>>5)<<5], __ATOMIC_RELAXED, __HIP_MEMORY_SCOPE_AGENT);
      okA &= (xv == ra); okB &= (xv == rb);
    }
    bool allA = (__ballot(okA != 0) == ~0ull);
    bool allB = (__ballot(okB != 0) == ~0ull);
    if (tid == 0)
      __hip_atomic_store(verdict, allA ? 2u : (allB ? 3u : 1u),
                         __ATOMIC_RELAXED, __HIP_MEMORY_SCOPE_AGENT);
  }
  // ---- all blocks poll the single verdict (acyclic -> deadlock-free) ----
  volatile unsigned* shm = (volatile unsigned*)lds;
  if (tid == 0) {
    unsigned vv;
    for (;;) {
      vv = __hip_atomic_load(verdict, __ATOMIC_RELAXED, __HIP_MEMORY_SCOPE_AGENT);
      if (vv != 0u) break;
      __builtin_amdgcn_s_sleep(2);
    }
    shm[0] = vv;
  }
  __syncthreads();
  const unsigned v = shm[0];
  __syncthreads();   // everyone has v before weight staging overwrites LDS

  if (v == 2u)        // mapping A verified: slab = bid&7 lives on one XCD
    run_loop<true >(x16, We, Wd, be, bd, h0, h1, out, stepFlags, stepGo, lds,
                    bid & 7, bid >> 3);
  else if (v == 3u)   // mapping B verified: slab = bid>>5 lives on one XCD
    run_loop<true >(x16, We, Wd, be, bd, h0, h1, out, stepFlags, stepGo, lds,
                    bid >> 5, bid & 31);
  else                // fallback: R6 LLC path (any block->XCD map)
    run_loop<false>(x16, We, Wd, be, bd, h0, h1, out, stepFlags, stepGo, lds,
                    bid & 7, bid >> 3);
}

// ---------------------------------------------------------------------------

extern "C" void kernel_launch(void* const* d_in, const int* in_sizes, int n_in,
                              void* d_out, int out_size, void* d_ws, size_t ws_size,
                              hipStream_t stream) {
  (void)in_sizes; (void)n_in; (void)out_size; (void)ws_size;
  const float* x   = (const float*)d_in[0];
  const float* Wih = (const float*)d_in[1];
  const float* Whh = (const float*)d_in[2];
  const float* bih = (const float*)d_in[3];
  const float* bhh = (const float*)d_in[4];
  const float* Wo  = (const float*)d_in[5];
  const float* bo  = (const float*)d_in[6];
  float* out = (float*)d_out;

  char* ws = (char*)d_ws;
  size_t off = 0;
  auto alloc = [&](size_t bytes) {
    char* p = ws + off;
    off += (bytes + 255) & ~(size_t)255;
    return p;
  };
  f16*   x16 = (f16*)  alloc((size_t)T_*B_*I_*2);
  f16*   hA  = (f16*)  alloc((size_t)B_*H_*2);
  f16*   hB  = (f16*)  alloc((size_t)B_*H_*2);
  f16*   We  = (f16*)  alloc((size_t)128*18*512*2);
  f16*   Wd  = (f16*)  alloc((size_t)160*16*512*2);
  float* Wf  = (float*)alloc((size_t)1536*512*4);
  float* be  = (float*)alloc(2048*4);
  float* bd  = (float*)alloc(2560*4);
  float* bf  = (float*)alloc(1536*4);
  size_t sync_base = off;
  unsigned* stepFlags = (unsigned*)alloc(256*64);  // (bm*32+g)*16, 64B padded
  unsigned* stepGo    = (unsigned*)alloc(8*64);
  unsigned* xcds      = (unsigned*)alloc(NBLK*4);
  unsigned* verdict   = (unsigned*)alloc(64);
  size_t sync_bytes = off - sync_base;

  hipMemsetAsync(ws + sync_base, 0, sync_bytes, stream);
  hipLaunchKernelGGL(k_zero_h,   dim3((B_*H_+255)/256),    dim3(256), 0, stream, hA);
  hipLaunchKernelGGL(k_cvt_x,    dim3((T_*B_*I_+255)/256), dim3(256), 0, stream, x, x16);
  hipLaunchKernelGGL(k_fuse,     dim3(1536*512/256),       dim3(256), 0, stream, Wo, Wih, Wf);
  hipLaunchKernelGGL(k_bf,       dim3(6),                  dim3(256), 0, stream, bo, Wih, bf);
  hipLaunchKernelGGL(k_pack_enc, dim3(128*18*512/256),     dim3(256), 0, stream, Whh, Wih, We);
  hipLaunchKernelGGL(k_pack_dec, dim3(160*16*512/256),     dim3(256), 0, stream, Whh, Wo, Wf, Wd);
  hipLaunchKernelGGL(k_bias_enc, dim3(8),                  dim3(256), 0, stream, bih, bhh, be);
  hipLaunchKernelGGL(k_bias_dec, dim3(10),                 dim3(256), 0, stream, bih, bhh, bo, bf, bd);

  hipLaunchKernelGGL(k_persist, dim3(NBLK), dim3(256), 0, stream,
                     x16, We, Wd, be, bd, hA, hB, out,
                     stepFlags, stepGo, xcds, verdict);
}

// Round 15
// 1788.691 us; speedup vs baseline: 1.9853x; 1.9853x over previous
//
#include <hip/hip_runtime.h>

typedef _Float16 f16;
typedef _Float16 f16x8 __attribute__((ext_vector_type(8)));
typedef float f32x4 __attribute__((ext_vector_type(4)));

#define B_ 512
#define T_ 128
#define I_ 64
#define H_ 512
#define O_ 64
#define L_ 300
#define OUTSTR (L_*O_)
#define NBLK 256

// ---------------------------------------------------------------------------
// Prologue kernels (verified R0/R1/R3). Packed B layout (MFMA 16x16x32 f16):
//   flat = ((ntile_global*KSTEPS + kstep)*64 + lane)*8 + elem
//   value = W[k][col], k = kstep*32 + (lane>>4)*8 + elem, col = lane&15
// ---------------------------------------------------------------------------

__global__ void k_zero_h(f16* h) {
  int i = blockIdx.x*256 + threadIdx.x;
  if (i < B_*H_) h[i] = (f16)0.f;
}

__global__ void k_cvt_x(const float* __restrict__ x, f16* __restrict__ x16) {
  int p = blockIdx.x*256 + threadIdx.x;
  if (p >= T_*B_*I_) return;
  int i = p & 63, b = (p >> 6) & 511, t = p >> 15;
  x16[p] = (f16)x[((size_t)b*T_ + t)*I_ + i];
}

__global__ void k_fuse(const float* __restrict__ Wo, const float* __restrict__ Wih,
                       float* __restrict__ Wf) {
  int p = blockIdx.x*256 + threadIdx.x;
  if (p >= 1536*512) return;
  int k = p & 511, j3 = p >> 9;
  float s = 0.f;
  for (int o = 0; o < 64; ++o) s += Wo[(size_t)o*H_ + k] * Wih[(size_t)j3*I_ + o];
  Wf[p] = s;
}

__global__ void k_bf(const float* __restrict__ bo, const float* __restrict__ Wih,
                     float* __restrict__ bf) {
  int j3 = blockIdx.x*256 + threadIdx.x;
  if (j3 >= 1536) return;
  float s = 0.f;
  for (int o = 0; o < 64; ++o) s += bo[o]*Wih[(size_t)j3*I_ + o];
  bf[j3] = s;
}

__global__ void k_pack_enc(const float* __restrict__ Whh, const float* __restrict__ Wih,
                           f16* __restrict__ We) {
  int p = blockIdx.x*256 + threadIdx.x;
  if (p >= 128*18*512) return;
  int i = p & 7, l = (p >> 3) & 63, ks = (p >> 9) % 18, ntg = p / (18*512);
  int g = ntg >> 2, nti = ntg & 3, c = l & 15;
  int j = g*16 + c, k = ks*32 + ((l>>4)<<3) + i;
  float v = 0.f;
  if (nti == 0)      v = (k < 512) ? Whh[(size_t)j*H_ + k]        : Wih[(size_t)j*I_ + (k-512)];
  else if (nti == 1) v = (k < 512) ? Whh[(size_t)(512+j)*H_ + k]  : Wih[(size_t)(512+j)*I_ + (k-512)];
  else if (nti == 2) v = (k < 512) ? Whh[(size_t)(1024+j)*H_ + k] : 0.f;
  else               v = (k >= 512)? Wih[(size_t)(1024+j)*I_ + (k-512)] : 0.f;
  We[p] = (f16)v;
}

__global__ void k_pack_dec(const float* __restrict__ Whh, const float* __restrict__ Wo,
                           const float* __restrict__ Wf, f16* __restrict__ Wd) {
  int p = blockIdx.x*256 + threadIdx.x;
  if (p >= 160*16*512) return;
  int i = p & 7, l = (p >> 3) & 63, ks = (p >> 9) & 15, ntg = p >> 13;
  int g = ntg/5, nti = ntg%5, c = l & 15;
  int j = g*16 + c, k = ks*32 + ((l>>4)<<3) + i;
  float v;
  if (nti == 0)      v = Whh[(size_t)j*H_+k]       + Wf[(size_t)j*512 + k];
  else if (nti == 1) v = Whh[(size_t)(512+j)*H_+k] + Wf[(size_t)(512+j)*512 + k];
  else if (nti == 2) v = Whh[(size_t)(1024+j)*H_+k];
  else if (nti == 3) v = Wf[(size_t)(1024+j)*512 + k];
  else               v = (c < 2) ? Wo[(size_t)(2*g+c)*H_ + k] : 0.f;
  Wd[p] = (f16)v;
}

__global__ void k_bias_enc(const float* __restrict__ bih, const float* __restrict__ bhh,
                           float* __restrict__ be) {
  int p = blockIdx.x*256 + threadIdx.x;
  if (p >= 2048) return;
  int c = p & 15, ntg = p >> 4, g = ntg >> 2, nti = ntg & 3, j = g*16 + c;
  float v;
  if (nti == 0)      v = bih[j] + bhh[j];
  else if (nti == 1) v = bih[512+j] + bhh[512+j];
  else if (nti == 2) v = bhh[1024+j];
  else               v = bih[1024+j];
  be[p] = v;
}

__global__ void k_bias_dec(const float* __restrict__ bih, const float* __restrict__ bhh,
                           const float* __restrict__ bo, const float* __restrict__ bf,
                           float* __restrict__ bd) {
  int p = blockIdx.x*256 + threadIdx.x;
  if (p >= 2560) return;
  int c = p & 15, ntg = p >> 4, g = ntg/5, nti = ntg%5, j = g*16 + c;
  float v;
  if (nti == 0)      v = bih[j] + bhh[j] + bf[j];
  else if (nti == 1) v = bih[512+j] + bhh[512+j] + bf[512+j];
  else if (nti == 2) v = bhh[1024+j];
  else if (nti == 3) v = bih[1024+j] + bf[1024+j];
  else               v = (c < 2) ? bo[2*g+c] : 0.f;
  bd[p] = v;
}

// ---------------------------------------------------------------------------
// R14: fine-grained producer/consumer flags replace the per-step barrier.
// flag[g]=t  <=>  block g stored its 16 columns of h_t (set after vmcnt(0)
// drain + block-wide syncthreads -> also implies all of g's step-(t-1) reads
// finished -> 2-buffer ping-pong remains WAR-safe; every block verifies all
// 32 flags >= t (two half-polls) before any step-t store).
// ks=0..7 needs producers g'=0..15 (half 0); ks=8..15 needs half 1 -> poll2
// sits mid-step and stragglers hide under the first 8 K-steps' MFMAs.
// Coherence rulebook (HW-proven R2..R13): publish = sc0/sc0sc1 write-through
// store; poll = sc0sc1 LOAD only (sc0-only load -> stale-L1 hang; atomic
// poll -> 0.5GB HBM write traffic); streamed data = sc0 within XCD.
// ---------------------------------------------------------------------------

__device__ __forceinline__ float sigmoidf_(float x){ return 1.f/(1.f + __expf(-x)); }
__device__ __forceinline__ float tanhf_(float x){ return 1.f - 2.f/(__expf(2.f*x) + 1.f); }

template<bool FA>
__device__ __forceinline__ f16x8 ldA(const f16* p) {     // coherent 16B load
  f16x8 r;
  if (FA) asm volatile("global_load_dwordx4 %0, %1, off sc0"     : "=&v"(r) : "v"(p));
  else    asm volatile("global_load_dwordx4 %0, %1, off sc0 sc1" : "=&v"(r) : "v"(p));
  return r;
}
__device__ __forceinline__ f16x8 ldP(const f16* p) {     // read-only (x16), cached
  f16x8 r;
  asm volatile("global_load_dwordx4 %0, %1, off" : "=&v"(r) : "v"(p));
  return r;
}
template<bool FA>
__device__ __forceinline__ void stH(f16* p, f16 h) {     // write-through 2B store
  unsigned b = (unsigned)__builtin_bit_cast(unsigned short, h);
  if (FA) asm volatile("global_store_short %0, %1, off sc0"     :: "v"(p), "v"(b) : "memory");
  else    asm volatile("global_store_short %0, %1, off sc0 sc1" :: "v"(p), "v"(b) : "memory");
}
__device__ __forceinline__ void vwait0() {
  asm volatile("s_waitcnt vmcnt(0)" ::: "memory");
  __builtin_amdgcn_sched_barrier(0);
}

// Per-wave poll: all 64 lanes read the half's 16 flag lines (4x dup), ballot.
// sc0sc1 loads (LLC-coherent; the ONLY proven poll flavor).
__device__ __forceinline__ void pollHalf(const unsigned* __restrict__ fs,
                                         int half, unsigned tgt) {
  const unsigned* pp = fs + (half*16 + (threadIdx.x & 15))*16;
  for (;;) {
    unsigned v;
    asm volatile("global_load_dword %0, %1, off sc0 sc1\n\ts_waitcnt vmcnt(0)"
                 : "=&v"(v) : "v"(pp) : "memory");
    if (__ballot(v >= tgt) == ~0ull) break;
  }
  __builtin_amdgcn_sched_barrier(0);
}

// Arrive: drain this block's h stores (all waves), then tid0 publishes flag.
__device__ __forceinline__ void arrive(unsigned* __restrict__ fs,
                                       int g, unsigned tgt) {
  asm volatile("s_waitcnt vmcnt(0)" ::: "memory");  // my waves' stores acked
  __syncthreads();                                  // all 4 waves drained
  if (threadIdx.x == 0) {
    unsigned* fp = fs + g*16;
    asm volatile("global_store_dword %0, %1, off sc0 sc1"
                 :: "v"(fp), "v"(tgt) : "memory");
  }
  __builtin_amdgcn_sched_barrier(0);
}

#define MFMA16(a,b,acc) __builtin_amdgcn_mfma_f32_16x16x32_f16(a, b, acc, 0, 0, 0)

template<bool FA>
__device__ __forceinline__ void run_loop(
    const f16* __restrict__ x16, const f16* __restrict__ We,
    const f16* __restrict__ Wd, const float* __restrict__ be,
    const float* __restrict__ bd, f16* __restrict__ h0, f16* __restrict__ h1,
    float* __restrict__ out, unsigned* __restrict__ fs,  // this slab's 32 flags
    f16* lds, int bm, int g) {
  const int tid = threadIdx.x, w = tid >> 6, lane = tid & 63;
  const int c = lane & 15, rq = lane >> 4;
  const int row0 = bm*64 + w*16 + c;       // A-fragment row
  const int rowb = bm*64 + w*16 + rq*4;    // C/D row base
  const int j = g*16 + c;

  // ---- encoder: stage K=512 h-part weights to LDS once; x-part in regs ----
  for (int it = 0; it < 16; ++it) {
    int idx = it*256 + tid;
    int nt = idx >> 10, r = idx & 1023;
    *(f16x8*)((char*)lds + (size_t)idx*16) =
        *(const f16x8*)((const char*)We + (size_t)(g*4+nt)*18432 + (size_t)r*16);
  }
  f16x8 bx0,bx1,bx2,bx3,bx4,bx5,bx6,bx7;
  {
    const char* base = (const char*)We + (size_t)lane*16 + 16*1024;
    bx0 = *(const f16x8*)(base + (size_t)(g*4+0)*18432);
    bx1 = *(const f16x8*)(base + (size_t)(g*4+1)*18432);
    bx2 = *(const f16x8*)(base + (size_t)(g*4+2)*18432);
    bx3 = *(const f16x8*)(base + (size_t)(g*4+3)*18432);
    bx4 = *(const f16x8*)(base + (size_t)(g*4+0)*18432 + 1024);
    bx5 = *(const f16x8*)(base + (size_t)(g*4+1)*18432 + 1024);
    bx6 = *(const f16x8*)(base + (size_t)(g*4+2)*18432 + 1024);
    bx7 = *(const f16x8*)(base + (size_t)(g*4+3)*18432 + 1024);
  }
  float br = be[(g*4+0)*16+c], bz = be[(g*4+1)*16+c];
  float bh = be[(g*4+2)*16+c], bi = be[(g*4+3)*16+c];
  float hprev[4] = {0.f, 0.f, 0.f, 0.f};   // h_in[rowb+i][j], owned by THIS
                                           // thread (h0 starts zeroed)
  __syncthreads();

  unsigned s = 0;   // global step index 0..426; flag[g]=t <=> h_t published
  for (int t = 0; t < T_; ++t, ++s) {
    const f16* hin  = (t & 1) ? h1 : h0;
    f16*       hout = (t & 1) ? h0 : h1;
    const f16* xt = x16 + (size_t)t*B_*I_;
    f32x4 a0={},a1={},a2={},a3={};
    f16x8 ha[16];
    // ---- half 0: producers g'=0..15 ----
    pollHalf(fs, 0, s);
    #pragma unroll
    for (int ks = 0; ks < 8; ++ks)
      ha[ks] = ldA<FA>(hin + (size_t)row0*H_ + ks*32 + (rq<<3));
    f16x8 ax = ldP(xt + (size_t)row0*I_ + (rq<<3));
    f16x8 ay = ldP(xt + (size_t)row0*I_ + 32 + (rq<<3));
    vwait0();
    a0 = MFMA16(ax, bx0, a0); a1 = MFMA16(ax, bx1, a1);
    a2 = MFMA16(ax, bx2, a2); a3 = MFMA16(ax, bx3, a3);
    a0 = MFMA16(ay, bx4, a0); a1 = MFMA16(ay, bx5, a1);
    a2 = MFMA16(ay, bx6, a2); a3 = MFMA16(ay, bx7, a3);
    #pragma unroll
    for (int ks = 0; ks < 8; ++ks) {
      a0 = MFMA16(ha[ks], *(const f16x8*)(lds + (0*16+ks)*512 + lane*8), a0);
      a1 = MFMA16(ha[ks], *(const f16x8*)(lds + (1*16+ks)*512 + lane*8), a1);
      a2 = MFMA16(ha[ks], *(const f16x8*)(lds + (2*16+ks)*512 + lane*8), a2);
      a3 = MFMA16(ha[ks], *(const f16x8*)(lds + (3*16+ks)*512 + lane*8), a3);
    }
    // ---- half 1: producers g'=16..31 (stragglers hid under half-0 MFMA) ----
    pollHalf(fs, 1, s);
    #pragma unroll
    for (int ks = 8; ks < 16; ++ks)
      ha[ks] = ldA<FA>(hin + (size_t)row0*H_ + ks*32 + (rq<<3));
    vwait0();
    #pragma unroll
    for (int ks = 8; ks < 16; ++ks) {
      a0 = MFMA16(ha[ks], *(const f16x8*)(lds + (0*16+ks)*512 + lane*8), a0);
      a1 = MFMA16(ha[ks], *(const f16x8*)(lds + (1*16+ks)*512 + lane*8), a1);
      a2 = MFMA16(ha[ks], *(const f16x8*)(lds + (2*16+ks)*512 + lane*8), a2);
      a3 = MFMA16(ha[ks], *(const f16x8*)(lds + (3*16+ks)*512 + lane*8), a3);
    }
    #pragma unroll
    for (int i = 0; i < 4; ++i) {
      float r = sigmoidf_(a0[i] + br);
      float z = sigmoidf_(a1[i] + bz);
      float n = tanhf_((a3[i] + bi) + r*(a2[i] + bh));
      f16 hv = (f16)((1.f - z)*n + z*hprev[i]);
      stH<FA>(hout + (size_t)(rowb+i)*H_ + j, hv);
      hprev[i] = (float)hv;
    }
    arrive(fs, g, s+1);
  }

  // ---- decoder: restage gate ntiles; y-ntile in regs ----
  __syncthreads();
  for (int it = 0; it < 16; ++it) {
    int idx = it*256 + tid;
    int nt = idx >> 10, r = idx & 1023;
    *(f16x8*)((char*)lds + (size_t)idx*16) =
        *(const f16x8*)((const char*)Wd + (size_t)(g*5+nt)*16384 + (size_t)r*16);
  }
  f16x8 yb[16];
  #pragma unroll
  for (int ks = 0; ks < 16; ++ks)
    yb[ks] = *(const f16x8*)((const char*)Wd + (size_t)(g*5+4)*16384
                             + (size_t)ks*1024 + (size_t)lane*16);
  float dr = bd[(g*5+0)*16+c], dz = bd[(g*5+1)*16+c];
  float dh = bd[(g*5+2)*16+c], di = bd[(g*5+3)*16+c], dy = bd[(g*5+4)*16+c];
  __syncthreads();

  for (int d = 0; d < L_-1; ++d, ++s) {
    const f16* hin  = (d & 1) ? h1 : h0;
    f16*       hout = (d & 1) ? h0 : h1;
    f32x4 a0={},a1={},a2={},a3={},a4={};
    f16x8 ha[16];
    pollHalf(fs, 0, s);
    #pragma unroll
    for (int ks = 0; ks < 8; ++ks)
      ha[ks] = ldA<FA>(hin + (size_t)row0*H_ + ks*32 + (rq<<3));
    vwait0();
    #pragma unroll
    for (int ks = 0; ks < 8; ++ks) {
      a0 = MFMA16(ha[ks], *(const f16x8*)(lds + (0*16+ks)*512 + lane*8), a0);
      a1 = MFMA16(ha[ks], *(const f16x8*)(lds + (1*16+ks)*512 + lane*8), a1);
      a2 = MFMA16(ha[ks], *(const f16x8*)(lds + (2*16+ks)*512 + lane*8), a2);
      a3 = MFMA16(ha[ks], *(const f16x8*)(lds + (3*16+ks)*512 + lane*8), a3);
      a4 = MFMA16(ha[ks], yb[ks], a4);
    }
    pollHalf(fs, 1, s);
    #pragma unroll
    for (int ks = 8; ks < 16; ++ks)
      ha[ks] = ldA<FA>(hin + (size_t)row0*H_ + ks*32 + (rq<<3));
    vwait0();
    #pragma unroll
    for (int ks = 8; ks < 16; ++ks) {
      a0 = MFMA16(ha[ks], *(const f16x8*)(lds + (0*16+ks)*512 + lane*8), a0);
      a1 = MFMA16(ha[ks], *(const f16x8*)(lds + (1*16+ks)*512 + lane*8), a1);
      a2 = MFMA16(ha[ks], *(const f16x8*)(lds + (2*16+ks)*512 + lane*8), a2);
      a3 = MFMA16(ha[ks], *(const f16x8*)(lds + (3*16+ks)*512 + lane*8), a3);
      a4 = MFMA16(ha[ks], yb[ks], a4);
    }
    float* yo = out + (size_t)d*O_;
    #pragma unroll
    for (int i = 0; i < 4; ++i) {
      float r = sigmoidf_(a0[i] + dr);
      float z = sigmoidf_(a1[i] + dz);
      float n = tanhf_((a3[i] + di) + r*(a2[i] + dh));
      f16 hv = (f16)((1.f - z)*n + z*hprev[i]);
      stH<FA>(hout + (size_t)(rowb+i)*H_ + j, hv);
      hprev[i] = (float)hv;
      if (c < 2) yo[(size_t)(rowb+i)*OUTSTR + 2*g + c] = a4[i] + dy;
    }
    arrive(fs, g, s+1);
  }

  // ---- final y projection from h1 (stores of step 426 -> flags >= 427) ----
  {
    pollHalf(fs, 0, s); pollHalf(fs, 1, s);   // s == 427 here
    f16x8 ha[16];
    #pragma unroll
    for (int ks = 0; ks < 16; ++ks)
      ha[ks] = ldA<FA>(h1 + (size_t)row0*H_ + ks*32 + (rq<<3));
    vwait0();
    f32x4 a4 = {};
    #pragma unroll
    for (int ks = 0; ks < 16; ++ks) a4 = MFMA16(ha[ks], yb[ks], a4);
    if (c < 2) {
      #pragma unroll
      for (int i = 0; i < 4; ++i)
        out[(size_t)(rowb+i)*OUTSTR + (size_t)(L_-1)*O_ + 2*g + c] = a4[i] + dy;
    }
  }
}

__global__ __launch_bounds__(256, 1) void k_persist(
    const f16* __restrict__ x16, const f16* __restrict__ We,
    const f16* __restrict__ Wd, const float* __restrict__ be,
    const float* __restrict__ bd, f16* __restrict__ h0, f16* __restrict__ h1,
    float* __restrict__ out, unsigned* __restrict__ stepFlags,
    unsigned* __restrict__ xcds, unsigned* __restrict__ verdict) {
  __shared__ f16 lds[32768];
  const int tid = threadIdx.x, bid = blockIdx.x;

  // ---- every block unconditionally publishes XCC_ID|8 (nonzero marker) ----
  if (tid == 0) {
    unsigned xcc;
    asm volatile("s_getreg_b32 %0, hwreg(HW_REG_XCC_ID)" : "=s"(xcc));
    __hip_atomic_store(&xcds[bid], (xcc & 7u) | 8u, __ATOMIC_RELAXED,
                       __HIP_MEMORY_SCOPE_AGENT);
  }
  // ---- block 0: wait all published, decide, publish verdict (acyclic) ----
  if (bid == 0 && tid < 64) {
    for (;;) {
      int ready = 1;
      for (int k2 = 0; k2 < 4; ++k2)
        ready &= (__hip_atomic_load(&xcds[tid*4 + k2], __ATOMIC_RELAXED,
                                    __HIP_MEMORY_SCOPE_AGENT) >= 8u);
      if (__ballot(ready != 0) == ~0ull) break;
      __builtin_amdgcn_s_sleep(2);
    }
    int okA = 1, okB = 1;
    for (int k2 = 0; k2 < 4; ++k2) {
      int b2 = tid*4 + k2;
      unsigned xv = __hip_atomic_load(&xcds[b2],         __ATOMIC_RELAXED, __HIP_MEMORY_SCOPE_AGENT);
      unsigned ra = __hip_atomic_load(&xcds[b2 & 7],     __ATOMIC_RELAXED, __HIP_MEMORY_SCOPE_AGENT);
      unsigned rb = __hip_atomic_load(&xcds[(b2>>5)<<5], __ATOMIC_RELAXED, __HIP_MEMORY_SCOPE_AGENT);
      okA &= (xv == ra); okB &= (xv == rb);
    }
    bool allA = (__ballot(okA != 0) == ~0ull);
    bool allB = (__ballot(okB != 0) == ~0ull);
    if (tid == 0)
      __hip_atomic_store(verdict, allA ? 2u : (allB ? 3u : 1u),
                         __ATOMIC_RELAXED, __HIP_MEMORY_SCOPE_AGENT);
  }
  // ---- all blocks poll the single verdict (acyclic -> deadlock-free) ----
  volatile unsigned* shm = (volatile unsigned*)lds;
  if (tid == 0) {
    unsigned vv;
    for (;;) {
      vv = __hip_atomic_load(verdict, __ATOMIC_RELAXED, __HIP_MEMORY_SCOPE_AGENT);
      if (vv != 0u) break;
      __builtin_amdgcn_s_sleep(2);
    }
    shm[0] = vv;
  }
  __syncthreads();
  const unsigned v = shm[0];
  __syncthreads();   // everyone has v before weight staging overwrites LDS

  if (v == 2u)        // mapping A verified: slab = bid&7 on one XCD
    run_loop<true >(x16, We, Wd, be, bd, h0, h1, out,
                    stepFlags + (bid & 7)*32*16, lds, bid & 7, bid >> 3);
  else if (v == 3u)   // mapping B verified: slab = bid>>5 on one XCD
    run_loop<true >(x16, We, Wd, be, bd, h0, h1, out,
                    stepFlags + (bid >> 5)*32*16, lds, bid >> 5, bid & 31);
  else                // fallback: all-sc0sc1 flavor (any block->XCD map)
    run_loop<false>(x16, We, Wd, be, bd, h0, h1, out,
                    stepFlags + (bid & 7)*32*16, lds, bid & 7, bid >> 3);
}

// ---------------------------------------------------------------------------

extern "C" void kernel_launch(void* const* d_in, const int* in_sizes, int n_in,
                              void* d_out, int out_size, void* d_ws, size_t ws_size,
                              hipStream_t stream) {
  (void)in_sizes; (void)n_in; (void)out_size; (void)ws_size;
  const float* x   = (const float*)d_in[0];
  const float* Wih = (const float*)d_in[1];
  const float* Whh = (const float*)d_in[2];
  const float* bih = (const float*)d_in[3];
  const float* bhh = (const float*)d_in[4];
  const float* Wo  = (const float*)d_in[5];
  const float* bo  = (const float*)d_in[6];
  float* out = (float*)d_out;

  char* ws = (char*)d_ws;
  size_t off = 0;
  auto alloc = [&](size_t bytes) {
    char* p = ws + off;
    off += (bytes + 255) & ~(size_t)255;
    return p;
  };
  f16*   x16 = (f16*)  alloc((size_t)T_*B_*I_*2);
  f16*   hA  = (f16*)  alloc((size_t)B_*H_*2);
  f16*   hB  = (f16*)  alloc((size_t)B_*H_*2);
  f16*   We  = (f16*)  alloc((size_t)128*18*512*2);
  f16*   Wd  = (f16*)  alloc((size_t)160*16*512*2);
  float* Wf  = (float*)alloc((size_t)1536*512*4);
  float* be  = (float*)alloc(2048*4);
  float* bd  = (float*)alloc(2560*4);
  float* bf  = (float*)alloc(1536*4);
  size_t sync_base = off;
  unsigned* stepFlags = (unsigned*)alloc(256*64);  // (bm*32+g)*16, 64B padded
  unsigned* xcds      = (unsigned*)alloc(NBLK*4);
  unsigned* verdict   = (unsigned*)alloc(64);
  size_t sync_bytes = off - sync_base;

  hipMemsetAsync(ws + sync_base, 0, sync_bytes, stream);
  hipLaunchKernelGGL(k_zero_h,   dim3((B_*H_+255)/256),    dim3(256), 0, stream, hA);
  hipLaunchKernelGGL(k_cvt_x,    dim3((T_*B_*I_+255)/256), dim3(256), 0, stream, x, x16);
  hipLaunchKernelGGL(k_fuse,     dim3(1536*512/256),       dim3(256), 0, stream, Wo, Wih, Wf);
  hipLaunchKernelGGL(k_bf,       dim3(6),                  dim3(256), 0, stream, bo, Wih, bf);
  hipLaunchKernelGGL(k_pack_enc, dim3(128*18*512/256),     dim3(256), 0, stream, Whh, Wih, We);
  hipLaunchKernelGGL(k_pack_dec, dim3(160*16*512/256),     dim3(256), 0, stream, Whh, Wo, Wf, Wd);
  hipLaunchKernelGGL(k_bias_enc, dim3(8),                  dim3(256), 0, stream, bih, bhh, be);
  hipLaunchKernelGGL(k_bias_dec, dim3(10),                 dim3(256), 0, stream, bih, bhh, bo, bf, bd);

  hipLaunchKernelGGL(k_persist, dim3(NBLK), dim3(256), 0, stream,
                     x16, We, Wd, be, bd, hA, hB, out,
                     stepFlags, xcds, verdict);
}